// Round 20
// baseline (185.684 us; speedup 1.0000x reference)
//
#include <hip/hip_runtime.h>
#include <hip/hip_bf16.h>
#include <math.h>

// Problem constants (B,C,H,W) = (2,64,128,128), R=2 -> K=24 neighbors.
#define NNODES 16384            // H*W
#define KE 24

typedef float f32x4 __attribute__((ext_vector_type(4)));
typedef unsigned u32x4 __attribute__((ext_vector_type(4)));
typedef __fp16 half2_t __attribute__((ext_vector_type(2)));      // cvt_pkrtz type
typedef _Float16 half8_t __attribute__((ext_vector_type(8)));    // MFMA operand type

union fragcast { u32x4 u; half8_t h; half2_t h2[4]; };

// ---------------------------------------------------------------------------
// A: per-node precompute as fp16-Dekker MFMA GEMM (verified R19, ~12us).
// ---------------------------------------------------------------------------
__global__ __launch_bounds__(256) void precompute_k(
    const float* __restrict__ x, const float* __restrict__ W1,
    const float* __restrict__ Wm, const float* __restrict__ b1,
    const float* __restrict__ bm,
    float* __restrict__ zsrc, float* __restrict__ ztgt, float* __restrict__ msg,
    float* __restrict__ zpos)
{
    __shared__ fragcast fragA[64 * 17];     // 16 slots/lane + pad (17.4 KB)
    __shared__ float otL[4][16 * 68];       // per-wave transpose tile (17.4 KB)

    const int t = threadIdx.x;
    const int l = t & 63;
    const int lcol = l & 15;
    const int lgrp = l >> 4;
    const int w = t >> 6;
    const int mat = blockIdx.x >> 8;        // grid = 3*256
    const int tile = blockIdx.x & 255;
    const int n0g = tile * 128;
    const int b = n0g >> 14;
    const int nl0 = n0g & (NNODES - 1);

    if (blockIdx.x == 0) {                  // zpos table
        for (int idx = t; idx < KE * 64; idx += 256) {
            int k = idx >> 6, h = idx & 63;
            int kk = k + (k >= 12 ? 1 : 0);
            int q5 = (kk * 52) >> 8;
            int dy = q5 - 2, dx = kk - 5 * q5 - 2;
            zpos[idx] = W1[h * 130 + 128] * (dx * 0.5f)
                      + W1[h * 130 + 129] * (dy * 0.5f);
        }
    }

    {
        const int mt = w;
        const int h = mt * 16 + lcol;
        const float* wrow = (mat == 0) ? (W1 + (size_t)h * 130)
                          : (mat == 1) ? (W1 + (size_t)h * 130 + 64)
                                       : (Wm + (size_t)h * 64);
        #pragma unroll
        for (int kt = 0; kt < 2; ++kt) {
            const float* wr = wrow + kt * 32 + lgrp * 8;
            fragcast fh, fl;
            #pragma unroll
            for (int d = 0; d < 4; ++d) {
                float e0 = wr[2 * d] * 64.f;
                float e1 = wr[2 * d + 1] * 64.f;
                half2_t hh = __builtin_amdgcn_cvt_pkrtz(e0, e1);
                fh.h2[d] = hh;
                fl.h2[d] = __builtin_amdgcn_cvt_pkrtz(e0 - (float)hh[0],
                                                      e1 - (float)hh[1]);
            }
            fragA[l * 17 + mt * 4 + kt * 2 + 0] = fh;
            fragA[l * 17 + mt * 4 + kt * 2 + 1] = fl;
        }
    }
    __syncthreads();

    float bv[4][4];
    #pragma unroll
    for (int mt = 0; mt < 4; ++mt)
        #pragma unroll
        for (int q = 0; q < 4; ++q) {
            int h = mt * 16 + lgrp * 4 + q;
            bv[mt][q] = (mat == 0) ? b1[h] : (mat == 2) ? bm[h] : 0.f;
        }

    const fragcast* fa = &fragA[l * 17];
    const float* xb = x + (size_t)b * 64 * NNODES + nl0;
    float* dst = (mat == 0) ? zsrc : (mat == 1) ? ztgt : msg;
    float* ot = &otL[w][0];

    #pragma unroll 1
    for (int nt = 0; nt < 2; ++nt) {
        const int nloc = w * 32 + nt * 16;

        fragcast Bh[2], Bl[2];
        #pragma unroll
        for (int kt = 0; kt < 2; ++kt) {
            const float* xc = xb + (size_t)(kt * 32 + lgrp * 8) * NNODES + nloc + lcol;
            float xv[8];
            #pragma unroll
            for (int i = 0; i < 8; ++i) xv[i] = xc[(size_t)i * NNODES];
            #pragma unroll
            for (int d = 0; d < 4; ++d) {
                half2_t hh = __builtin_amdgcn_cvt_pkrtz(xv[2 * d], xv[2 * d + 1]);
                Bh[kt].h2[d] = hh;
                Bl[kt].h2[d] = __builtin_amdgcn_cvt_pkrtz(xv[2 * d] - (float)hh[0],
                                                          xv[2 * d + 1] - (float)hh[1]);
            }
        }

        #pragma unroll
        for (int mt = 0; mt < 4; ++mt) {
            f32x4 acc = {0.f, 0.f, 0.f, 0.f};
            #pragma unroll
            for (int kt = 0; kt < 2; ++kt) {
                fragcast Ah = fa[mt * 4 + kt * 2 + 0];
                fragcast Al = fa[mt * 4 + kt * 2 + 1];
                acc = __builtin_amdgcn_mfma_f32_16x16x32_f16(Ah.h, Bh[kt].h, acc, 0, 0, 0);
                acc = __builtin_amdgcn_mfma_f32_16x16x32_f16(Al.h, Bh[kt].h, acc, 0, 0, 0);
                acc = __builtin_amdgcn_mfma_f32_16x16x32_f16(Ah.h, Bl[kt].h, acc, 0, 0, 0);
            }
            #pragma unroll
            for (int q = 0; q < 4; ++q) {
                float v = fmaf(acc[q], 0.015625f, bv[mt][q]);   // /64 compensation
                if (mat == 2) v = fmaxf(v, 0.f);
                ot[lcol * 68 + mt * 16 + lgrp * 4 + q] = v;
            }
        }

        {
            int nn = l >> 2, qt = l & 3;
            float* gout = dst + (size_t)(n0g + nloc + nn) * 64 + qt * 16;
            #pragma unroll
            for (int j = 0; j < 4; ++j) {
                f32x4 vv = *(const f32x4*)&ot[nn * 68 + qt * 16 + j * 4];
                *(float4*)(gout + j * 4) = make_float4(vv[0], vv[1], vv[2], vv[3]);
            }
        }
    }
}

// ---------------------------------------------------------------------------
// B: scorer (frozen at its best: 42.3us, absmax 0.0078).
// ---------------------------------------------------------------------------
__global__ __launch_bounds__(256, 1) void score_k(
    const float* __restrict__ zsrc, const float* __restrict__ ztgt,
    const float* __restrict__ zpos, const float* __restrict__ W2,
    const float* __restrict__ b2, const float* __restrict__ W3,
    const float* __restrict__ b3, float* __restrict__ scores)
{
    __shared__ fragcast fraglds[64 * 13];
    __shared__ float zpl[24 * 68];

    const int t = threadIdx.x;
    const int l = t & 63;
    const int lcol = l & 15;
    const int lgrp = l >> 4;
    const int w = t >> 6;
    const int wave = blockIdx.x * 4 + w;

    #pragma unroll
    for (int r = 0; r < 6; ++r) {
        int idx = r * 256 + t;
        zpl[(idx >> 6) * 68 + (idx & 63)] = zpos[idx];
    }
    {
        const int jt = w >> 1, kt = w & 1;
        fragcast fh, fl;
        const float* wr = W2 + (size_t)(jt * 16 + lcol) * 64 + kt * 32 + lgrp * 8;
        #pragma unroll
        for (int d = 0; d < 4; ++d) {
            float e0 = wr[2 * d] * 64.f;
            float e1 = wr[2 * d + 1] * 64.f;
            half2_t hh = __builtin_amdgcn_cvt_pkrtz(e0, e1);
            float r0 = e0 - (float)hh[0];
            float r1 = e1 - (float)hh[1];
            fh.h2[d] = hh;
            fl.h2[d] = __builtin_amdgcn_cvt_pkrtz(r0, r1);
        }
        fraglds[l * 13 + 0 + jt * 2 + kt] = fh;
        fraglds[l * 13 + 4 + jt * 2 + kt] = fl;
    }
    __syncthreads();

    const fragcast* fb = &fraglds[l * 13];
    const f32x4 b2l0 = *(const f32x4*)(b2 + lgrp * 4);
    const f32x4 b2l1 = *(const f32x4*)(b2 + 16 + lgrp * 4);
    const f32x4 w3l0 = *(const f32x4*)(W3 + lgrp * 4);
    const f32x4 w3l1 = *(const f32x4*)(W3 + 16 + lgrp * 4);
    const float b3s = b3[0];

    const int node0 = wave * 2;

    int kArr[3];
    float4 zsv[3][4], ztv[3][4];
    #pragma unroll
    for (int Mt = 0; Mt < 3; ++Mt) {
        const int ke = Mt * 16 + lcol;
        const int nsel = (ke >= 24) ? 1 : 0;
        const int node = node0 + nsel;
        const int k = ke - 24 * nsel;
        const int bb = node >> 14;
        const int nl = node & (NNODES - 1);
        const int yy = nl >> 7, xx = nl & 127;
        const int kk = k + (k >= 12 ? 1 : 0);
        const int q5 = (kk * 52) >> 8;
        const int dy = q5 - 2, dx = kk - 5 * q5 - 2;
        const int ny = min(max(yy + dy, 0), 127);
        const int nx = min(max(xx + dx, 0), 127);
        const int nbn = (bb << 14) + (ny << 7) + nx;
        kArr[Mt] = k;
        const float* zs = zsrc + (size_t)node * 64 + lgrp * 8;
        const float* zt = ztgt + (size_t)nbn * 64 + lgrp * 8;
        zsv[Mt][0] = *(const float4*)(zs);
        zsv[Mt][1] = *(const float4*)(zs + 4);
        zsv[Mt][2] = *(const float4*)(zs + 32);
        zsv[Mt][3] = *(const float4*)(zs + 36);
        ztv[Mt][0] = *(const float4*)(zt);
        ztv[Mt][1] = *(const float4*)(zt + 4);
        ztv[Mt][2] = *(const float4*)(zt + 32);
        ztv[Mt][3] = *(const float4*)(zt + 36);
    }

    #pragma unroll
    for (int Mt = 0; Mt < 3; ++Mt) {
        const float* zp = &zpl[kArr[Mt] * 68 + lgrp * 8];

        f32x4 ac0A = {0.f,0.f,0.f,0.f}, ac0B = {0.f,0.f,0.f,0.f};
        f32x4 ac1A = {0.f,0.f,0.f,0.f}, ac1B = {0.f,0.f,0.f,0.f};

        #pragma unroll
        for (int kt = 0; kt < 2; ++kt) {
            float4 a0 = zsv[Mt][2 * kt], a1 = zsv[Mt][2 * kt + 1];
            float4 t0 = ztv[Mt][2 * kt], t1 = ztv[Mt][2 * kt + 1];
            float4 p0 = *(const float4*)(zp + kt * 32);
            float4 p1 = *(const float4*)(zp + kt * 32 + 4);
            float v[8];
            v[0] = fmaxf(a0.x + t0.x + p0.x, 0.f);
            v[1] = fmaxf(a0.y + t0.y + p0.y, 0.f);
            v[2] = fmaxf(a0.z + t0.z + p0.z, 0.f);
            v[3] = fmaxf(a0.w + t0.w + p0.w, 0.f);
            v[4] = fmaxf(a1.x + t1.x + p1.x, 0.f);
            v[5] = fmaxf(a1.y + t1.y + p1.y, 0.f);
            v[6] = fmaxf(a1.z + t1.z + p1.z, 0.f);
            v[7] = fmaxf(a1.w + t1.w + p1.w, 0.f);

            fragcast Bh, Bl;
            #pragma unroll
            for (int d = 0; d < 4; ++d) {
                float e0 = v[2 * d], e1 = v[2 * d + 1];
                half2_t hh = __builtin_amdgcn_cvt_pkrtz(e0, e1);
                float r0 = e0 - (float)hh[0];
                float r1 = e1 - (float)hh[1];
                Bh.h2[d] = hh;
                Bl.h2[d] = __builtin_amdgcn_cvt_pkrtz(r0, r1);
            }

            ac0A = __builtin_amdgcn_mfma_f32_16x16x32_f16(fb[0 + kt].h, Bh.h, ac0A, 0, 0, 0);
            ac1A = __builtin_amdgcn_mfma_f32_16x16x32_f16(fb[2 + kt].h, Bh.h, ac1A, 0, 0, 0);
            ac0B = __builtin_amdgcn_mfma_f32_16x16x32_f16(fb[4 + kt].h, Bh.h, ac0B, 0, 0, 0);
            ac1B = __builtin_amdgcn_mfma_f32_16x16x32_f16(fb[6 + kt].h, Bh.h, ac1B, 0, 0, 0);
            ac0B = __builtin_amdgcn_mfma_f32_16x16x32_f16(fb[0 + kt].h, Bl.h, ac0B, 0, 0, 0);
            ac1B = __builtin_amdgcn_mfma_f32_16x16x32_f16(fb[2 + kt].h, Bl.h, ac1B, 0, 0, 0);
        }

        const f32x4 s0 = ac0A + ac0B;
        const f32x4 s1 = ac1A + ac1B;
        float sacc = 0.f;
        #pragma unroll
        for (int q = 0; q < 4; ++q) {
            sacc = fmaf(fmaxf(fmaf(s0[q], 0.015625f, b2l0[q]), 0.f), w3l0[q], sacc);
            sacc = fmaf(fmaxf(fmaf(s1[q], 0.015625f, b2l1[q]), 0.f), w3l1[q], sacc);
        }
        sacc += __shfl_xor(sacc, 16);
        sacc += __shfl_xor(sacc, 32);
        float sig = 1.f / (1.f + expf(-(sacc + b3s)));
        if (l < 16)
            scores[(size_t)node0 * 24 + Mt * 16 + l] = sig;
    }
}

// ---------------------------------------------------------------------------
// C: aggregation. 16-node row-aligned blocks; msg 5x20 window staged in LDS
//    (25.6 KB, coalesced float4; 3.8x row reuse) -> gathers become
//    conflict-free ds_read_b32. Arithmetic order identical to previous.
// ---------------------------------------------------------------------------
__global__ __launch_bounds__(256) void agg_k(
    const float* __restrict__ x, const float* __restrict__ scores,
    const float* __restrict__ msg, const float* __restrict__ Wo,
    const float* __restrict__ bo, const float* __restrict__ thrp,
    float* __restrict__ out)
{
    __shared__ float mwin[100 * 64];    // 25.6 KB: 5x20 clamped node window
    __shared__ float sc[384];
    __shared__ float wle[384];
    __shared__ float sumw[16];
    __shared__ float aggL[16][64];
    __shared__ float ot[16 * 68];

    const int t = threadIdx.x;
    const int blkbase = blockIdx.x * 16;      // 16 consecutive nodes, same row
    const int b = blkbase >> 14;
    const int y = (blkbase >> 7) & 127;
    const int x0 = blkbase & 127;
    const int nl0 = blkbase & (NNODES - 1);
    const float thr_v = 1.f / (1.f + expf(-thrp[0]));

    // stage msg window: rows (y-2..y+2) x cols (x0-2..x0+17), clamped.
    for (int i = t; i < 1600; i += 256) {
        int row = i >> 4, f4 = i & 15;
        int wy = (row * 3277) >> 16;          // row / 20 for row < 100
        int cx = row - wy * 20;
        int gy = min(max(y + wy - 2, 0), 127);
        int gx = min(max(x0 + cx - 2, 0), 127);
        int gn = (b << 14) + (gy << 7) + gx;
        *(float4*)&mwin[row * 64 + f4 * 4] =
            *(const float4*)(msg + (size_t)gn * 64 + f4 * 4);
    }
    // stage scores
    #pragma unroll
    for (int rep = 0; rep < 2; ++rep) {
        int e = rep * 256 + t;
        if (e < 384) sc[e] = scores[(size_t)blkbase * 24 + e];
    }
    __syncthreads();

    // edge weights (rank/count/threshold, tie-stable)
    #pragma unroll
    for (int rep = 0; rep < 2; ++rep) {
        int e = rep * 256 + t;
        if (e < 384) {
            int nl = (int)(((unsigned)(e >> 3) * 171u) >> 9);   // e/24
            int k = e - nl * 24;
            float s_e = sc[e];
            int rank = 0, cnt = 0;
            #pragma unroll
            for (int j = 0; j < 24; ++j) {
                float sj = sc[nl * 24 + j];
                rank += (sj > s_e || (sj == s_e && j < k)) ? 1 : 0;
                cnt  += (sj >= thr_v) ? 1 : 0;
            }
            bool mask = (cnt > 8) ? (rank < 8)
                      : ((cnt < 3) ? (rank < 3) : (s_e >= thr_v));
            float keep = 1.f / (1.f + expf(-(s_e - thr_v) * 10.f));
            wle[e] = mask ? s_e * keep : 0.f;
        }
    }
    __syncthreads();

    if (t < 16) {
        float s = 0.f;
        #pragma unroll
        for (int k = 0; k < 24; ++k) s += wle[t * 24 + k];
        sumw[t] = s + 1e-6f;
    }
    __syncthreads();

    // weighted gather from LDS window (lane = channel -> conflict-free)
    {
        const int c = t & 63, w = t >> 6;
        #pragma unroll
        for (int it = 0; it < 4; ++it) {
            int nl = w * 4 + it;
            float acc = 0.f;
            #pragma unroll
            for (int k = 0; k < 24; ++k) {
                int kk = k + (k >= 12 ? 1 : 0);
                int q5 = (kk * 52) >> 8;
                int dy = q5 - 2, dx = kk - 5 * q5 - 2;
                int row = (dy + 2) * 20 + nl + dx + 2;
                acc = fmaf(wle[nl * 24 + k], mwin[row * 64 + c], acc);
            }
            aggL[nl][c] = acc / sumw[nl];
        }
    }
    __syncthreads();

    // out = x + agg @ Wo.T + bo
    {
        const int o = t & 63, g4 = t >> 6;
        const float4* wr = (const float4*)(Wo + (size_t)o * 64);
        #pragma unroll
        for (int it = 0; it < 4; ++it) {
            int nl = g4 + it * 4;
            const float4* ar = (const float4*)aggL[nl];
            float a0 = 0.f, a1 = 0.f, a2 = 0.f, a3 = 0.f;
            #pragma unroll
            for (int c4 = 0; c4 < 16; ++c4) {
                float4 wv = wr[c4];
                float4 av = ar[c4];
                a0 = fmaf(av.x, wv.x, a0);
                a1 = fmaf(av.y, wv.y, a1);
                a2 = fmaf(av.z, wv.z, a2);
                a3 = fmaf(av.w, wv.w, a3);
            }
            float v = (a0 + a1) + (a2 + a3) + bo[o]
                    + x[(size_t)b * 64 * NNODES + (size_t)o * NNODES + nl0 + nl];
            ot[nl * 68 + o] = v;
        }
    }
    __syncthreads();

    // coalesced stores (64B per o-row per block)
    {
        int o = t >> 2, jj = t & 3;
        float4 v = make_float4(ot[(4 * jj + 0) * 68 + o], ot[(4 * jj + 1) * 68 + o],
                               ot[(4 * jj + 2) * 68 + o], ot[(4 * jj + 3) * 68 + o]);
        *(float4*)(out + (size_t)b * 64 * NNODES + (size_t)o * NNODES + nl0 + 4 * jj) = v;
    }
}

// ---------------------------------------------------------------------------
extern "C" void kernel_launch(void* const* d_in, const int* in_sizes, int n_in,
                              void* d_out, int out_size, void* d_ws, size_t ws_size,
                              hipStream_t stream)
{
    const float* x   = (const float*)d_in[0];
    const float* W1  = (const float*)d_in[1];
    const float* b1  = (const float*)d_in[2];
    const float* W2  = (const float*)d_in[3];
    const float* b2  = (const float*)d_in[4];
    const float* W3  = (const float*)d_in[5];
    const float* b3  = (const float*)d_in[6];
    const float* thr = (const float*)d_in[7];
    const float* Wm  = (const float*)d_in[8];
    const float* bm  = (const float*)d_in[9];
    const float* Wo  = (const float*)d_in[10];
    const float* bo  = (const float*)d_in[11];
    float* out = (float*)d_out;
    float* ws  = (float*)d_ws;

    // ws layout (floats): zsrc[2M] ztgt[2M] msg[2M] scores[768K] zpos[1536]
    float* zsrc   = ws;
    float* ztgt   = ws + 2097152;
    float* msg    = ws + 4194304;
    float* scores = ws + 6291456;
    float* zpos   = ws + 7077888;

    hipLaunchKernelGGL(precompute_k, dim3(768), dim3(256), 0, stream,
                       x, W1, Wm, b1, bm, zsrc, ztgt, msg, zpos);
    hipLaunchKernelGGL(score_k, dim3(4096), dim3(256), 0, stream,
                       zsrc, ztgt, zpos, W2, b2, W3, b3, scores);
    hipLaunchKernelGGL(agg_k, dim3(2048), dim3(256), 0, stream,
                       x, scores, msg, Wo, bo, thr, out);
}

// Round 21
// 84.820 us; speedup vs baseline: 2.1892x; 2.1892x over previous
//
#include <hip/hip_runtime.h>
#include <hip/hip_bf16.h>
#include <math.h>

// Problem constants (B,C,H,W) = (2,64,128,128), R=2 -> K=24 neighbors.
#define NNODES 16384            // H*W
#define KE 24

typedef float f32x4 __attribute__((ext_vector_type(4)));
typedef unsigned u32x4 __attribute__((ext_vector_type(4)));
typedef __fp16 half2_t __attribute__((ext_vector_type(2)));      // cvt_pkrtz type
typedef _Float16 half8_t __attribute__((ext_vector_type(8)));    // MFMA operand type

union fragcast { u32x4 u; half8_t h; half2_t h2[4]; };

// ---------------------------------------------------------------------------
// A: per-node precompute as fp16-Dekker MFMA GEMM (verified R19, ~12us).
// ---------------------------------------------------------------------------
__global__ __launch_bounds__(256) void precompute_k(
    const float* __restrict__ x, const float* __restrict__ W1,
    const float* __restrict__ Wm, const float* __restrict__ b1,
    const float* __restrict__ bm,
    float* __restrict__ zsrc, float* __restrict__ ztgt, float* __restrict__ msg,
    float* __restrict__ zpos)
{
    __shared__ fragcast fragA[64 * 17];     // 16 slots/lane + pad (17.4 KB)
    __shared__ float otL[4][16 * 68];       // per-wave transpose tile (17.4 KB)

    const int t = threadIdx.x;
    const int l = t & 63;
    const int lcol = l & 15;
    const int lgrp = l >> 4;
    const int w = t >> 6;
    const int mat = blockIdx.x >> 8;        // grid = 3*256
    const int tile = blockIdx.x & 255;
    const int n0g = tile * 128;
    const int b = n0g >> 14;
    const int nl0 = n0g & (NNODES - 1);

    if (blockIdx.x == 0) {                  // zpos table
        for (int idx = t; idx < KE * 64; idx += 256) {
            int k = idx >> 6, h = idx & 63;
            int kk = k + (k >= 12 ? 1 : 0);
            int q5 = (kk * 52) >> 8;
            int dy = q5 - 2, dx = kk - 5 * q5 - 2;
            zpos[idx] = W1[h * 130 + 128] * (dx * 0.5f)
                      + W1[h * 130 + 129] * (dy * 0.5f);
        }
    }

    {
        const int mt = w;
        const int h = mt * 16 + lcol;
        const float* wrow = (mat == 0) ? (W1 + (size_t)h * 130)
                          : (mat == 1) ? (W1 + (size_t)h * 130 + 64)
                                       : (Wm + (size_t)h * 64);
        #pragma unroll
        for (int kt = 0; kt < 2; ++kt) {
            const float* wr = wrow + kt * 32 + lgrp * 8;
            fragcast fh, fl;
            #pragma unroll
            for (int d = 0; d < 4; ++d) {
                float e0 = wr[2 * d] * 64.f;
                float e1 = wr[2 * d + 1] * 64.f;
                half2_t hh = __builtin_amdgcn_cvt_pkrtz(e0, e1);
                fh.h2[d] = hh;
                fl.h2[d] = __builtin_amdgcn_cvt_pkrtz(e0 - (float)hh[0],
                                                      e1 - (float)hh[1]);
            }
            fragA[l * 17 + mt * 4 + kt * 2 + 0] = fh;
            fragA[l * 17 + mt * 4 + kt * 2 + 1] = fl;
        }
    }
    __syncthreads();

    float bv[4][4];
    #pragma unroll
    for (int mt = 0; mt < 4; ++mt)
        #pragma unroll
        for (int q = 0; q < 4; ++q) {
            int h = mt * 16 + lgrp * 4 + q;
            bv[mt][q] = (mat == 0) ? b1[h] : (mat == 2) ? bm[h] : 0.f;
        }

    const fragcast* fa = &fragA[l * 17];
    const float* xb = x + (size_t)b * 64 * NNODES + nl0;
    float* dst = (mat == 0) ? zsrc : (mat == 1) ? ztgt : msg;
    float* ot = &otL[w][0];

    #pragma unroll 1
    for (int nt = 0; nt < 2; ++nt) {
        const int nloc = w * 32 + nt * 16;

        fragcast Bh[2], Bl[2];
        #pragma unroll
        for (int kt = 0; kt < 2; ++kt) {
            const float* xc = xb + (size_t)(kt * 32 + lgrp * 8) * NNODES + nloc + lcol;
            float xv[8];
            #pragma unroll
            for (int i = 0; i < 8; ++i) xv[i] = xc[(size_t)i * NNODES];
            #pragma unroll
            for (int d = 0; d < 4; ++d) {
                half2_t hh = __builtin_amdgcn_cvt_pkrtz(xv[2 * d], xv[2 * d + 1]);
                Bh[kt].h2[d] = hh;
                Bl[kt].h2[d] = __builtin_amdgcn_cvt_pkrtz(xv[2 * d] - (float)hh[0],
                                                          xv[2 * d + 1] - (float)hh[1]);
            }
        }

        #pragma unroll
        for (int mt = 0; mt < 4; ++mt) {
            f32x4 acc = {0.f, 0.f, 0.f, 0.f};
            #pragma unroll
            for (int kt = 0; kt < 2; ++kt) {
                fragcast Ah = fa[mt * 4 + kt * 2 + 0];
                fragcast Al = fa[mt * 4 + kt * 2 + 1];
                acc = __builtin_amdgcn_mfma_f32_16x16x32_f16(Ah.h, Bh[kt].h, acc, 0, 0, 0);
                acc = __builtin_amdgcn_mfma_f32_16x16x32_f16(Al.h, Bh[kt].h, acc, 0, 0, 0);
                acc = __builtin_amdgcn_mfma_f32_16x16x32_f16(Ah.h, Bl[kt].h, acc, 0, 0, 0);
            }
            #pragma unroll
            for (int q = 0; q < 4; ++q) {
                float v = fmaf(acc[q], 0.015625f, bv[mt][q]);   // /64 compensation
                if (mat == 2) v = fmaxf(v, 0.f);
                ot[lcol * 68 + mt * 16 + lgrp * 4 + q] = v;
            }
        }

        {
            int nn = l >> 2, qt = l & 3;
            float* gout = dst + (size_t)(n0g + nloc + nn) * 64 + qt * 16;
            #pragma unroll
            for (int j = 0; j < 4; ++j) {
                f32x4 vv = *(const f32x4*)&ot[nn * 68 + qt * 16 + j * 4];
                *(float4*)(gout + j * 4) = make_float4(vv[0], vv[1], vv[2], vv[3]);
            }
        }
    }
}

// ---------------------------------------------------------------------------
// B: scorer (frozen at its best: 42.3us, absmax 0.0078).
// ---------------------------------------------------------------------------
__global__ __launch_bounds__(256, 1) void score_k(
    const float* __restrict__ zsrc, const float* __restrict__ ztgt,
    const float* __restrict__ zpos, const float* __restrict__ W2,
    const float* __restrict__ b2, const float* __restrict__ W3,
    const float* __restrict__ b3, float* __restrict__ scores)
{
    __shared__ fragcast fraglds[64 * 13];
    __shared__ float zpl[24 * 68];

    const int t = threadIdx.x;
    const int l = t & 63;
    const int lcol = l & 15;
    const int lgrp = l >> 4;
    const int w = t >> 6;
    const int wave = blockIdx.x * 4 + w;

    #pragma unroll
    for (int r = 0; r < 6; ++r) {
        int idx = r * 256 + t;
        zpl[(idx >> 6) * 68 + (idx & 63)] = zpos[idx];
    }
    {
        const int jt = w >> 1, kt = w & 1;
        fragcast fh, fl;
        const float* wr = W2 + (size_t)(jt * 16 + lcol) * 64 + kt * 32 + lgrp * 8;
        #pragma unroll
        for (int d = 0; d < 4; ++d) {
            float e0 = wr[2 * d] * 64.f;
            float e1 = wr[2 * d + 1] * 64.f;
            half2_t hh = __builtin_amdgcn_cvt_pkrtz(e0, e1);
            float r0 = e0 - (float)hh[0];
            float r1 = e1 - (float)hh[1];
            fh.h2[d] = hh;
            fl.h2[d] = __builtin_amdgcn_cvt_pkrtz(r0, r1);
        }
        fraglds[l * 13 + 0 + jt * 2 + kt] = fh;
        fraglds[l * 13 + 4 + jt * 2 + kt] = fl;
    }
    __syncthreads();

    const fragcast* fb = &fraglds[l * 13];
    const f32x4 b2l0 = *(const f32x4*)(b2 + lgrp * 4);
    const f32x4 b2l1 = *(const f32x4*)(b2 + 16 + lgrp * 4);
    const f32x4 w3l0 = *(const f32x4*)(W3 + lgrp * 4);
    const f32x4 w3l1 = *(const f32x4*)(W3 + 16 + lgrp * 4);
    const float b3s = b3[0];

    const int node0 = wave * 2;

    int kArr[3];
    float4 zsv[3][4], ztv[3][4];
    #pragma unroll
    for (int Mt = 0; Mt < 3; ++Mt) {
        const int ke = Mt * 16 + lcol;
        const int nsel = (ke >= 24) ? 1 : 0;
        const int node = node0 + nsel;
        const int k = ke - 24 * nsel;
        const int bb = node >> 14;
        const int nl = node & (NNODES - 1);
        const int yy = nl >> 7, xx = nl & 127;
        const int kk = k + (k >= 12 ? 1 : 0);
        const int q5 = (kk * 52) >> 8;
        const int dy = q5 - 2, dx = kk - 5 * q5 - 2;
        const int ny = min(max(yy + dy, 0), 127);
        const int nx = min(max(xx + dx, 0), 127);
        const int nbn = (bb << 14) + (ny << 7) + nx;
        kArr[Mt] = k;
        const float* zs = zsrc + (size_t)node * 64 + lgrp * 8;
        const float* zt = ztgt + (size_t)nbn * 64 + lgrp * 8;
        zsv[Mt][0] = *(const float4*)(zs);
        zsv[Mt][1] = *(const float4*)(zs + 4);
        zsv[Mt][2] = *(const float4*)(zs + 32);
        zsv[Mt][3] = *(const float4*)(zs + 36);
        ztv[Mt][0] = *(const float4*)(zt);
        ztv[Mt][1] = *(const float4*)(zt + 4);
        ztv[Mt][2] = *(const float4*)(zt + 32);
        ztv[Mt][3] = *(const float4*)(zt + 36);
    }

    #pragma unroll
    for (int Mt = 0; Mt < 3; ++Mt) {
        const float* zp = &zpl[kArr[Mt] * 68 + lgrp * 8];

        f32x4 ac0A = {0.f,0.f,0.f,0.f}, ac0B = {0.f,0.f,0.f,0.f};
        f32x4 ac1A = {0.f,0.f,0.f,0.f}, ac1B = {0.f,0.f,0.f,0.f};

        #pragma unroll
        for (int kt = 0; kt < 2; ++kt) {
            float4 a0 = zsv[Mt][2 * kt], a1 = zsv[Mt][2 * kt + 1];
            float4 t0 = ztv[Mt][2 * kt], t1 = ztv[Mt][2 * kt + 1];
            float4 p0 = *(const float4*)(zp + kt * 32);
            float4 p1 = *(const float4*)(zp + kt * 32 + 4);
            float v[8];
            v[0] = fmaxf(a0.x + t0.x + p0.x, 0.f);
            v[1] = fmaxf(a0.y + t0.y + p0.y, 0.f);
            v[2] = fmaxf(a0.z + t0.z + p0.z, 0.f);
            v[3] = fmaxf(a0.w + t0.w + p0.w, 0.f);
            v[4] = fmaxf(a1.x + t1.x + p1.x, 0.f);
            v[5] = fmaxf(a1.y + t1.y + p1.y, 0.f);
            v[6] = fmaxf(a1.z + t1.z + p1.z, 0.f);
            v[7] = fmaxf(a1.w + t1.w + p1.w, 0.f);

            fragcast Bh, Bl;
            #pragma unroll
            for (int d = 0; d < 4; ++d) {
                float e0 = v[2 * d], e1 = v[2 * d + 1];
                half2_t hh = __builtin_amdgcn_cvt_pkrtz(e0, e1);
                float r0 = e0 - (float)hh[0];
                float r1 = e1 - (float)hh[1];
                Bh.h2[d] = hh;
                Bl.h2[d] = __builtin_amdgcn_cvt_pkrtz(r0, r1);
            }

            ac0A = __builtin_amdgcn_mfma_f32_16x16x32_f16(fb[0 + kt].h, Bh.h, ac0A, 0, 0, 0);
            ac1A = __builtin_amdgcn_mfma_f32_16x16x32_f16(fb[2 + kt].h, Bh.h, ac1A, 0, 0, 0);
            ac0B = __builtin_amdgcn_mfma_f32_16x16x32_f16(fb[4 + kt].h, Bh.h, ac0B, 0, 0, 0);
            ac1B = __builtin_amdgcn_mfma_f32_16x16x32_f16(fb[6 + kt].h, Bh.h, ac1B, 0, 0, 0);
            ac0B = __builtin_amdgcn_mfma_f32_16x16x32_f16(fb[0 + kt].h, Bl.h, ac0B, 0, 0, 0);
            ac1B = __builtin_amdgcn_mfma_f32_16x16x32_f16(fb[2 + kt].h, Bl.h, ac1B, 0, 0, 0);
        }

        const f32x4 s0 = ac0A + ac0B;
        const f32x4 s1 = ac1A + ac1B;
        float sacc = 0.f;
        #pragma unroll
        for (int q = 0; q < 4; ++q) {
            sacc = fmaf(fmaxf(fmaf(s0[q], 0.015625f, b2l0[q]), 0.f), w3l0[q], sacc);
            sacc = fmaf(fmaxf(fmaf(s1[q], 0.015625f, b2l1[q]), 0.f), w3l1[q], sacc);
        }
        sacc += __shfl_xor(sacc, 16);
        sacc += __shfl_xor(sacc, 32);
        float sig = 1.f / (1.f + expf(-(sacc + b3s)));
        if (l < 16)
            scores[(size_t)node0 * 24 + Mt * 16 + l] = sig;
    }
}

// ---------------------------------------------------------------------------
// C: per-node rank/mask/weights + weighted msg aggregation + Wo + residual.
//    (R13 structure: 32-node blocks, direct global gathers — proven in the
//    85.0us R19 total; the windowed-LDS variant regressed 8x.)
// ---------------------------------------------------------------------------
__global__ __launch_bounds__(256) void agg_k(
    const float* __restrict__ x, const float* __restrict__ scores,
    const float* __restrict__ msg, const float* __restrict__ Wo,
    const float* __restrict__ bo, const float* __restrict__ thrp,
    float* __restrict__ out)
{
    __shared__ float sc[768];
    __shared__ float wl[768];
    __shared__ float sumw[32];
    __shared__ float aggL[32][64];
    __shared__ float ot[64][33];

    const int t = threadIdx.x;
    const int n0 = blockIdx.x * 32;
    const int b = n0 >> 14;
    const int nl0 = n0 & (NNODES - 1);
    const float thr_v = 1.f / (1.f + expf(-thrp[0]));

    #pragma unroll
    for (int rep = 0; rep < 3; ++rep)
        sc[rep * 256 + t] = scores[(size_t)n0 * 24 + rep * 256 + t];
    __syncthreads();

    #pragma unroll
    for (int rep = 0; rep < 3; ++rep) {
        int e = rep * 256 + t;
        int nl = (int)(((unsigned)(e >> 3) * 171u) >> 9);   // e/24 for e<768
        int k = e - nl * 24;
        float s_e = sc[e];
        int rank = 0, cnt = 0;
        #pragma unroll
        for (int j = 0; j < 24; ++j) {
            float sj = sc[nl * 24 + j];
            rank += (sj > s_e || (sj == s_e && j < k)) ? 1 : 0;
            cnt  += (sj >= thr_v) ? 1 : 0;
        }
        bool mask = (cnt > 8) ? (rank < 8)
                  : ((cnt < 3) ? (rank < 3) : (s_e >= thr_v));
        float keep = 1.f / (1.f + expf(-(s_e - thr_v) * 10.f));
        wl[e] = mask ? s_e * keep : 0.f;
    }
    __syncthreads();

    if (t < 32) {
        float s = 0.f;
        #pragma unroll
        for (int k = 0; k < 24; ++k) s += wl[t * 24 + k];
        sumw[t] = s + 1e-6f;
    }
    __syncthreads();

    const int lane = t & 63;
    const int g4 = t >> 6;

    #pragma unroll
    for (int it = 0; it < 8; ++it) {
        int nl = g4 + it * 4;
        int nn = nl0 + nl;
        int yy = nn >> 7, xx = nn & 127;
        float acc = 0.f;
        #pragma unroll
        for (int k = 0; k < 24; ++k) {
            int kk = k + (k >= 12 ? 1 : 0);
            int q5 = (kk * 52) >> 8;
            int dy = q5 - 2, dx = kk - 5 * q5 - 2;
            int ny = min(max(yy + dy, 0), 127);
            int nx = min(max(xx + dx, 0), 127);
            int nb = (b << 14) + (ny << 7) + nx;
            acc = fmaf(wl[nl * 24 + k], msg[(size_t)nb * 64 + lane], acc);
        }
        aggL[nl][lane] = acc / sumw[nl];
    }

    float4 wo[16];
    #pragma unroll
    for (int c4 = 0; c4 < 16; ++c4) wo[c4] = ((const float4*)Wo)[lane * 16 + c4];
    __syncthreads();

    #pragma unroll
    for (int it = 0; it < 8; ++it) {
        int nl = g4 + it * 4;
        const float4* ar = (const float4*)aggL[nl];
        float a0 = 0.f, a1 = 0.f, a2 = 0.f, a3 = 0.f;
        #pragma unroll
        for (int c4 = 0; c4 < 16; ++c4) {
            float4 wv = wo[c4];
            float4 av = ar[c4];
            a0 = fmaf(av.x, wv.x, a0);
            a1 = fmaf(av.y, wv.y, a1);
            a2 = fmaf(av.z, wv.z, a2);
            a3 = fmaf(av.w, wv.w, a3);
        }
        float v = (a0 + a1) + (a2 + a3) + bo[lane]
                + x[(size_t)b * 64 * NNODES + (size_t)lane * NNODES + nl0 + nl];
        ot[lane][nl] = v;
    }
    __syncthreads();

    #pragma unroll
    for (int rep = 0; rep < 2; ++rep) {
        int idx = rep * 256 + t;
        int o = idx >> 3, p = idx & 7;
        float4 v = make_float4(ot[o][4 * p + 0], ot[o][4 * p + 1],
                               ot[o][4 * p + 2], ot[o][4 * p + 3]);
        *(float4*)(out + (size_t)b * 64 * NNODES + (size_t)o * NNODES + nl0 + 4 * p) = v;
    }
}

// ---------------------------------------------------------------------------
extern "C" void kernel_launch(void* const* d_in, const int* in_sizes, int n_in,
                              void* d_out, int out_size, void* d_ws, size_t ws_size,
                              hipStream_t stream)
{
    const float* x   = (const float*)d_in[0];
    const float* W1  = (const float*)d_in[1];
    const float* b1  = (const float*)d_in[2];
    const float* W2  = (const float*)d_in[3];
    const float* b2  = (const float*)d_in[4];
    const float* W3  = (const float*)d_in[5];
    const float* b3  = (const float*)d_in[6];
    const float* thr = (const float*)d_in[7];
    const float* Wm  = (const float*)d_in[8];
    const float* bm  = (const float*)d_in[9];
    const float* Wo  = (const float*)d_in[10];
    const float* bo  = (const float*)d_in[11];
    float* out = (float*)d_out;
    float* ws  = (float*)d_ws;

    // ws layout (floats): zsrc[2M] ztgt[2M] msg[2M] scores[768K] zpos[1536]
    float* zsrc   = ws;
    float* ztgt   = ws + 2097152;
    float* msg    = ws + 4194304;
    float* scores = ws + 6291456;
    float* zpos   = ws + 7077888;

    hipLaunchKernelGGL(precompute_k, dim3(768), dim3(256), 0, stream,
                       x, W1, Wm, b1, bm, zsrc, ztgt, msg, zpos);
    hipLaunchKernelGGL(score_k, dim3(4096), dim3(256), 0, stream,
                       zsrc, ztgt, zpos, W2, b2, W3, b3, scores);
    hipLaunchKernelGGL(agg_k, dim3(1024), dim3(256), 0, stream,
                       x, scores, msg, Wo, bo, thr, out);
}